// Round 1
// baseline (351.432 us; speedup 1.0000x reference)
//
#include <hip/hip_runtime.h>
#include <hip/hip_bf16.h>
#include <stdint.h>

// EdgeMessage: message[e,m] = sum_v (edges[e,:]@W[m*64+v,:] + b[m*64+v]) * vertices[e,v]
// R7: column-split occupancy fix on top of R6's flatmm register-direct W stream.
//  - grid (E/64, 2): wave y owns output columns m in [32y, 32y+32) (n-frags {2y,2y+1}).
//    -> 3126 waves (12.2/CU, ~3/SIMD) vs 1563 (1.5/SIMD): TLP to hide L2 latency on
//       the W stream. Total W L2 traffic UNCHANGED (each wave reads its 512 KB half).
//  - per v-step: 8 B-frag loads + 32 MFMA; wA/wB 4-frag half-step double buffer
//    (16-MFMA shadow ~310 SIMD-cyc > ~200 cyc L2 latency).
//  - regs: acc 4x2 (32 AGPR), wA/wB 32, xh 64 -> ~150-160 total, 3 waves/SIMD.
//  - V from own Vtx row, f32->f16 chunk of 8 per 8 steps, prefetched 1 chunk ahead.
//  - bias folded as 2 extra K-steps (column subset only).

typedef _Float16 f16;
typedef __attribute__((ext_vector_type(2))) _Float16 f16x2;
typedef __attribute__((ext_vector_type(8))) _Float16 f16x8;
typedef __attribute__((ext_vector_type(4))) float f32x4;

#define MSG_D 64
#define VTX_D 64
#define EDG_D 128

__device__ __forceinline__ f16x8 cvt8(float4 a, float4 d) {
  return (f16x8){(f16)a.x, (f16)a.y, (f16)a.z, (f16)a.w,
                 (f16)d.x, (f16)d.y, (f16)d.z, (f16)d.w};
}

// ---- prep: W -> fragment stream; b -> bias frags (layout same as R5/R6) ----
// Wh granule tid = (v*16 + c)*64 + lane (c = s*4+n): f16[8] =
//   W[(n*16+ln)*64 + v][s*32 + q*8 + j], lane = q*16+ln.
__global__ void prep_w(const float* __restrict__ W, const float* __restrict__ b,
                       f16* __restrict__ Wh, f16* __restrict__ Bh) {
  int tid = blockIdx.x * 256 + threadIdx.x;
  if (tid < 65536) {
    int L = tid & 63, n = (tid >> 6) & 3, s = (tid >> 8) & 3, v = tid >> 10;
    int q = L >> 4, ln = L & 15;
    const float* src = W + (size_t)((n * 16 + ln) * 64 + v) * 128 + s * 32 + q * 8;
    float4 a = *(const float4*)src, d = *(const float4*)(src + 4);
    *(f16x8*)(Wh + (size_t)tid * 8) = cvt8(a, d);
  } else if (tid < 66048) {
    int t2 = tid - 65536;
    int L = t2 & 63, n = (t2 >> 6) & 3, s2 = t2 >> 8;
    int q = L >> 4, ln = L & 15;
    const float* src = b + (n * 16 + ln) * 64 + s2 * 32 + q * 8;
    float4 a = *(const float4*)src, d = *(const float4*)(src + 4);
    *(f16x8*)(Bh + (size_t)t2 * 8) = cvt8(a, d);
  }
}

// ---- main kernel: 1 wave = 64 edges x 32 cols, no LDS, no barriers ----
__global__ __launch_bounds__(64, 3) void edge_msg_flat(
    const float* __restrict__ Vtx, const float* __restrict__ Xe,
    const f16* __restrict__ Wh, const f16* __restrict__ Bh,
    float* __restrict__ out, int E)
{
  const int lane = threadIdx.x;
  const int q = lane >> 4, ln = lane & 15;
  const int eoff = blockIdx.x * 64;
  const int nb0 = blockIdx.y << 1;   // this wave's n-frags: {nb0, nb0+1}

  // X fragments f16 (A[m=ln][k=q*8+j] per t,s), rows clamped
  int er[4];
  f16x8 xh[4][4];
  #pragma unroll
  for (int t = 0; t < 4; ++t) {
    int e = eoff + 16 * t + ln;
    er[t] = e < E ? e : E - 1;
    const float* xr = Xe + (size_t)er[t] * EDG_D;
    #pragma unroll
    for (int s = 0; s < 4; ++s) {
      float4 a = *(const float4*)(xr + s * 32 + q * 8);
      float4 d = *(const float4*)(xr + s * 32 + q * 8 + 4);
      xh[t][s] = cvt8(a, d);
    }
  }

  f32x4 acc[4][2];
  #pragma unroll
  for (int t = 0; t < 4; ++t)
    #pragma unroll
    for (int nn = 0; nn < 2; ++nn) acc[t][nn] = (f32x4){0.f, 0.f, 0.f, 0.f};

  // frag (v, s, nn) at wp + v*8192 + s*2048 + nn*512   (f16 units)
  const f16* wp = Wh + (size_t)lane * 8 + (size_t)nb0 * 512;

  f16x8 wA[4], wB[4];
  #pragma unroll
  for (int c = 0; c < 4; ++c)
    wA[c] = *(const f16x8*)(wp + (c >> 1) * 2048 + (c & 1) * 512);

  // V chunk 0 (v = 0..7) per t, f32 -> f16x8
  f16x8 vrow[4];
  #pragma unroll
  for (int t = 0; t < 4; ++t) {
    const float* vsrc = Vtx + (size_t)er[t] * VTX_D;
    float4 a = *(const float4*)(vsrc), d = *(const float4*)(vsrc + 4);
    vrow[t] = cvt8(a, d);
  }

  #pragma unroll 1
  for (int c8 = 0; c8 < 8; ++c8) {
    // prefetch next V chunk (consumed 8 steps later)
    f16x8 vnext[4];
    if (c8 < 7) {
      #pragma unroll
      for (int t = 0; t < 4; ++t) {
        const float* vsrc = Vtx + (size_t)er[t] * VTX_D + (c8 + 1) * 8;
        float4 a = *(const float4*)(vsrc), d = *(const float4*)(vsrc + 4);
        vnext[t] = cvt8(a, d);
      }
    }

    #pragma unroll
    for (int j = 0; j < 8; ++j) {
      const int v = c8 * 8 + j;
      const f16* wrow  = wp + (size_t)v * 8192;
      const f16* wrowN = wp + (size_t)(v < 63 ? v + 1 : 63) * 8192;

      // load second half of step v (s = 2,3) -> wB
      #pragma unroll
      for (int c = 0; c < 4; ++c)
        wB[c] = *(const f16x8*)(wrow + 4096 + (c >> 1) * 2048 + (c & 1) * 512);

      // per-edge V broadcast for this v (static element extract)
      f16x2 hv[4];
      #pragma unroll
      for (int t = 0; t < 4; ++t) { f16 h = vrow[t][j]; hv[t] = (f16x2){h, h}; }

      // compute s = 0,1 from wA
      #pragma unroll
      for (int s = 0; s < 2; ++s) {
        f16x8 af[4];
        #pragma unroll
        for (int t = 0; t < 4; ++t) {
          union { f16x8 v8; f16x2 h2[4]; } x, r;
          x.v8 = xh[t][s];
          r.h2[0] = hv[t] * x.h2[0];
          r.h2[1] = hv[t] * x.h2[1];
          r.h2[2] = hv[t] * x.h2[2];
          r.h2[3] = hv[t] * x.h2[3];
          af[t] = r.v8;
        }
        #pragma unroll
        for (int nn = 0; nn < 2; ++nn)
          #pragma unroll
          for (int t = 0; t < 4; ++t)
            acc[t][nn] = __builtin_amdgcn_mfma_f32_16x16x32_f16(af[t], wA[s * 2 + nn], acc[t][nn], 0, 0, 0);
      }

      // load first half of step v+1 (s = 0,1) -> wA
      #pragma unroll
      for (int c = 0; c < 4; ++c)
        wA[c] = *(const f16x8*)(wrowN + (c >> 1) * 2048 + (c & 1) * 512);

      // compute s = 2,3 from wB
      #pragma unroll
      for (int s = 2; s < 4; ++s) {
        f16x8 af[4];
        #pragma unroll
        for (int t = 0; t < 4; ++t) {
          union { f16x8 v8; f16x2 h2[4]; } x, r;
          x.v8 = xh[t][s];
          r.h2[0] = hv[t] * x.h2[0];
          r.h2[1] = hv[t] * x.h2[1];
          r.h2[2] = hv[t] * x.h2[2];
          r.h2[3] = hv[t] * x.h2[3];
          af[t] = r.v8;
        }
        #pragma unroll
        for (int nn = 0; nn < 2; ++nn)
          #pragma unroll
          for (int t = 0; t < 4; ++t)
            acc[t][nn] = __builtin_amdgcn_mfma_f32_16x16x32_f16(af[t], wB[(s - 2) * 2 + nn], acc[t][nn], 0, 0, 0);
      }
    }

    #pragma unroll
    for (int t = 0; t < 4; ++t) vrow[t] = vnext[t];
  }

  // bias: 2 K-steps, A = V-frags (original layout), B = Bh frags (column subset)
  #pragma unroll
  for (int s2 = 0; s2 < 2; ++s2) {
    f16x8 av[4];
    #pragma unroll
    for (int t = 0; t < 4; ++t) {
      const float* vr2 = Vtx + (size_t)er[t] * VTX_D + s2 * 32 + q * 8;
      float4 a = *(const float4*)vr2, d = *(const float4*)(vr2 + 4);
      av[t] = cvt8(a, d);
    }
    #pragma unroll
    for (int nn = 0; nn < 2; ++nn) {
      int n = nb0 + nn;
      f16x8 bf = *(const f16x8*)(Bh + (size_t)((s2 * 4 + n) * 64 + lane) * 8);
      #pragma unroll
      for (int t = 0; t < 4; ++t)
        acc[t][nn] = __builtin_amdgcn_mfma_f32_16x16x32_f16(av[t], bf, acc[t][nn], 0, 0, 0);
    }
  }

  // store: C layout col=lane&15 (m), row=q*4+r (edge) [m89-verified]
  #pragma unroll
  for (int t = 0; t < 4; ++t)
    #pragma unroll
    for (int r = 0; r < 4; ++r) {
      int e = eoff + 16 * t + 4 * q + r;
      if (e < E) {
        float* orow = out + (size_t)e * MSG_D;
        #pragma unroll
        for (int nn = 0; nn < 2; ++nn) orow[(nb0 + nn) * 16 + ln] = acc[t][nn][r];
      }
    }
}

// ---- fallback (workspace too small / unexpected shape): exact fp32 ----
__global__ void edge_msg_naive(const float* __restrict__ Vtx, const float* __restrict__ Xe,
                               const float* __restrict__ W, const float* __restrict__ b,
                               float* __restrict__ out, int E) {
  __shared__ float xs[EDG_D];
  __shared__ float vs[VTX_D];
  int e = blockIdx.x;
  int m = threadIdx.x;
  for (int i = m; i < EDG_D; i += 64) xs[i] = Xe[(size_t)e * EDG_D + i];
  for (int i = m; i < VTX_D; i += 64) vs[i] = Vtx[(size_t)e * VTX_D + i];
  __syncthreads();
  float s = 0.f;
  for (int v = 0; v < VTX_D; ++v) {
    const float* wr = W + (size_t)(m * 64 + v) * EDG_D;
    float p = b[m * 64 + v];
    for (int k = 0; k < EDG_D; ++k) p += xs[k] * wr[k];
    s += p * vs[v];
  }
  out[(size_t)e * MSG_D + m] = s;
}

extern "C" void kernel_launch(void* const* d_in, const int* in_sizes, int n_in,
                              void* d_out, int out_size, void* d_ws, size_t ws_size,
                              hipStream_t stream) {
  const float* Vtx = (const float*)d_in[0];   // [E, 64]
  const float* Xe  = (const float*)d_in[1];   // [E, 128]
  const float* W   = (const float*)d_in[2];   // [4096, 128]
  const float* b   = (const float*)d_in[3];   // [4096]
  float* out = (float*)d_out;

  const int E  = in_sizes[0] / VTX_D;
  const int nW = in_sizes[2];                 // 524288
  const int nb = in_sizes[3];                 // 4096

  const size_t needW = (size_t)(524288 + 4096) * sizeof(f16);   // ~1.01 MB

  if (nW != 524288 || nb != 4096 || ws_size < needW) {
    edge_msg_naive<<<E, 64, 0, stream>>>(Vtx, Xe, W, b, out, E);
    return;
  }

  f16* Wh = (f16*)d_ws;
  f16* Bh = Wh + 524288;

  prep_w<<<258, 256, 0, stream>>>(W, b, Wh, Bh);

  int blocks_x = (E + 63) / 64;
  dim3 grid(blocks_x, 2);
  edge_msg_flat<<<grid, 64, 0, stream>>>(Vtx, Xe, Wh, Bh, out, E);
}

// Round 2
// 206.019 us; speedup vs baseline: 1.7058x; 1.7058x over previous
//
#include <hip/hip_runtime.h>
#include <stdint.h>

// EdgeMessage: message[e,m] = sum_v (edges[e,:]@W[m*64+v,:] + b[m*64+v]) * vertices[e,v]
// R8: LDS-shared W stream (revert R7 column split; attack latency, not width).
//  - block = 4 waves x 64 edges = 256 edges; each wave computes 64e x 64m (R6 tile).
//  - W frags staged per v-step (16 KB) into a 3-buffer LDS ring via global_load_lds,
//    prefetch depth 2, counted vmcnt(4) + raw s_barrier (loads in flight across
//    barriers, never drained mid-loop). W L2 traffic /4 vs R6.
//  - V staged once, transposed f16 in LDS [64][256]: steady loop has ZERO
//    compiler-managed global loads -> no conservative vmcnt drains possible.
//  - consumption: 16 ds_read_b128/step (4 per s-group, shadowed by 16 MFMA each).
//  - LDS 80 KB -> 2 blocks/CU -> all 391 blocks resident at t=0, 2 independent
//    waves/SIMD on doubled CUs (barrier-decoupled latency cover).

typedef _Float16 f16;
typedef __attribute__((ext_vector_type(2))) _Float16 f16x2;
typedef __attribute__((ext_vector_type(8))) _Float16 f16x8;
typedef __attribute__((ext_vector_type(4))) float f32x4;

#define MSG_D 64
#define VTX_D 64
#define EDG_D 128

__device__ __forceinline__ f16x8 cvt8(float4 a, float4 d) {
  return (f16x8){(f16)a.x, (f16)a.y, (f16)a.z, (f16)a.w,
                 (f16)d.x, (f16)d.y, (f16)d.z, (f16)d.w};
}

// ---- prep: W -> fragment stream; b -> bias frags (layout same as R5/R6) ----
// Wh granule tid = (v*16 + c)*64 + lane (c = s*4+n): f16[8] =
//   W[(n*16+ln)*64 + v][s*32 + q*8 + j], lane = q*16+ln.
__global__ void prep_w(const float* __restrict__ W, const float* __restrict__ b,
                       f16* __restrict__ Wh, f16* __restrict__ Bh) {
  int tid = blockIdx.x * 256 + threadIdx.x;
  if (tid < 65536) {
    int L = tid & 63, n = (tid >> 6) & 3, s = (tid >> 8) & 3, v = tid >> 10;
    int q = L >> 4, ln = L & 15;
    const float* src = W + (size_t)((n * 16 + ln) * 64 + v) * 128 + s * 32 + q * 8;
    float4 a = *(const float4*)src, d = *(const float4*)(src + 4);
    *(f16x8*)(Wh + (size_t)tid * 8) = cvt8(a, d);
  } else if (tid < 66048) {
    int t2 = tid - 65536;
    int L = t2 & 63, n = (t2 >> 6) & 3, s2 = t2 >> 8;
    int q = L >> 4, ln = L & 15;
    const float* src = b + (n * 16 + ln) * 64 + s2 * 32 + q * 8;
    float4 a = *(const float4*)src, d = *(const float4*)(src + 4);
    *(f16x8*)(Bh + (size_t)t2 * 8) = cvt8(a, d);
  }
}

// async global->LDS, 16B per lane, wave-uniform LDS base (+lane*16 implicit)
typedef __attribute__((address_space(1))) const void GV;
typedef __attribute__((address_space(3))) void LV;
__device__ __forceinline__ void gload_lds16(const void* g, void* l) {
  __builtin_amdgcn_global_load_lds((GV*)g, (LV*)l, 16, 0, 0);
}

// ---- main kernel: 256 threads = 4 waves; LDS-shared W stream ----
__global__ __launch_bounds__(256, 2) void edge_msg_lds(
    const float* __restrict__ Vtx, const float* __restrict__ Xe,
    const f16* __restrict__ Wh, const f16* __restrict__ Bh,
    float* __restrict__ out, int E)
{
  __shared__ f16 Wsh[3 * 8192];   // 48 KB: ring of 3 step-buffers (16 KB each)
  __shared__ f16 Vt[64 * 256];    // 32 KB: V transposed f16 [v][local_e]

  const int tid = threadIdx.x;
  const int wid = tid >> 6, lane = tid & 63;
  const int q = lane >> 4, ln = lane & 15;
  const int eblk = blockIdx.x * 256;
  const int eoff = eblk + wid * 64;

  // ---- X fragments f16 (A[m=ln][k=q*8+j] per t,s), rows clamped ----
  int er[4];
  f16x8 xh[4][4];
  #pragma unroll
  for (int t = 0; t < 4; ++t) {
    int e = eoff + 16 * t + ln;
    er[t] = e < E ? e : E - 1;
    const float* xr = Xe + (size_t)er[t] * EDG_D;
    #pragma unroll
    for (int s = 0; s < 4; ++s) {
      float4 a = *(const float4*)(xr + s * 32 + q * 8);
      float4 d = *(const float4*)(xr + s * 32 + q * 8 + 4);
      xh[t][s] = cvt8(a, d);
    }
  }

  // ---- stage V transposed (each thread stages its own local edge row) ----
  {
    int e = eblk + tid;
    int ec = e < E ? e : E - 1;
    const float* vr = Vtx + (size_t)ec * VTX_D;
    #pragma unroll
    for (int k = 0; k < 16; ++k) {
      float4 a = *(const float4*)(vr + k * 4);
      Vt[(k * 4 + 0) * 256 + tid] = (f16)a.x;
      Vt[(k * 4 + 1) * 256 + tid] = (f16)a.y;
      Vt[(k * 4 + 2) * 256 + tid] = (f16)a.z;
      Vt[(k * 4 + 3) * 256 + tid] = (f16)a.w;
    }
  }

  f32x4 acc[4][4];
  #pragma unroll
  for (int t = 0; t < 4; ++t)
    #pragma unroll
    for (int n = 0; n < 4; ++n) acc[t][n] = (f32x4){0.f, 0.f, 0.f, 0.f};

  // V writes visible to all waves before loop
  asm volatile("s_waitcnt lgkmcnt(0)" ::: "memory");
  __builtin_amdgcn_s_barrier();
  asm volatile("" ::: "memory");

  // ---- prefetch W steps 0,1 (wave wid stages granules c = wid*4..wid*4+3) ----
  // Wh bytes: granule (v,c) at v*16384 + c*1024 + lane*16
  {
    const char* gbase = (const char*)Wh + (size_t)(wid * 4) * 1024 + (size_t)lane * 16;
    char* lbase = (char*)&Wsh[0] + (wid * 4) * 1024;
    #pragma unroll
    for (int c = 0; c < 4; ++c) gload_lds16(gbase + c * 1024, lbase + c * 1024);
    #pragma unroll
    for (int c = 0; c < 4; ++c)
      gload_lds16(gbase + 16384 + c * 1024, lbase + 2 * 8192 + c * 1024);  // +8192 f16 = 16384 B
  }

  int bo = 0;  // f16 offset of current step buffer in Wsh (0 / 8192 / 16384)

  #pragma unroll 1
  for (int v = 0; v < 64; ++v) {
    // own granules for step v complete (4 newer stay in flight), then block sync
    if (v == 63) asm volatile("s_waitcnt vmcnt(0)" ::: "memory");
    else         asm volatile("s_waitcnt vmcnt(4)" ::: "memory");
    __builtin_amdgcn_s_barrier();
    asm volatile("" ::: "memory");   // no LDS reads / stage issues above this point

    // stage step v+2 into buf (v+2)%3
    if (v < 62) {
      int so = bo + 2 * 8192;
      if (so >= 3 * 8192) so -= 3 * 8192;
      const char* gbase = (const char*)Wh + (size_t)(v + 2) * 16384 +
                          (size_t)(wid * 4) * 1024 + (size_t)lane * 16;
      char* lbase = (char*)&Wsh[so] + (wid * 4) * 1024;
      #pragma unroll
      for (int c = 0; c < 4; ++c) gload_lds16(gbase + c * 1024, lbase + c * 1024);
    }

    // per-edge V broadcast for this v (from transposed LDS, conflict-free)
    f16x2 hv[4];
    #pragma unroll
    for (int t = 0; t < 4; ++t) {
      f16 h = Vt[v * 256 + wid * 64 + 16 * t + ln];
      hv[t] = (f16x2){h, h};
    }

    const f16* wb = &Wsh[bo + lane * 8];
    #pragma unroll
    for (int s = 0; s < 4; ++s) {
      f16x8 bf[4];
      #pragma unroll
      for (int n = 0; n < 4; ++n) bf[n] = *(const f16x8*)(wb + (s * 4 + n) * 512);

      f16x8 af[4];
      #pragma unroll
      for (int t = 0; t < 4; ++t) {
        union { f16x8 v8; f16x2 h2[4]; } x, r;
        x.v8 = xh[t][s];
        r.h2[0] = hv[t] * x.h2[0];
        r.h2[1] = hv[t] * x.h2[1];
        r.h2[2] = hv[t] * x.h2[2];
        r.h2[3] = hv[t] * x.h2[3];
        af[t] = r.v8;
      }
      #pragma unroll
      for (int n = 0; n < 4; ++n)
        #pragma unroll
        for (int t = 0; t < 4; ++t)
          acc[t][n] = __builtin_amdgcn_mfma_f32_16x16x32_f16(af[t], bf[n], acc[t][n], 0, 0, 0);
    }

    bo += 8192;
    if (bo >= 3 * 8192) bo -= 3 * 8192;
  }

  // ---- bias: 2 K-steps, A = V-frags (original layout), B = Bh frags ----
  #pragma unroll
  for (int s2 = 0; s2 < 2; ++s2) {
    f16x8 av[4];
    #pragma unroll
    for (int t = 0; t < 4; ++t) {
      const float* vr2 = Vtx + (size_t)er[t] * VTX_D + s2 * 32 + q * 8;
      float4 a = *(const float4*)vr2, d = *(const float4*)(vr2 + 4);
      av[t] = cvt8(a, d);
    }
    #pragma unroll
    for (int n = 0; n < 4; ++n) {
      f16x8 bfb = *(const f16x8*)(Bh + (size_t)((s2 * 4 + n) * 64 + lane) * 8);
      #pragma unroll
      for (int t = 0; t < 4; ++t)
        acc[t][n] = __builtin_amdgcn_mfma_f32_16x16x32_f16(av[t], bfb, acc[t][n], 0, 0, 0);
    }
  }

  // ---- store: C layout col=lane&15 (m), row=q*4+r (edge) [m89-verified] ----
  #pragma unroll
  for (int t = 0; t < 4; ++t)
    #pragma unroll
    for (int r = 0; r < 4; ++r) {
      int e = eoff + 16 * t + 4 * q + r;
      if (e < E) {
        float* orow = out + (size_t)e * MSG_D;
        #pragma unroll
        for (int n = 0; n < 4; ++n) orow[n * 16 + ln] = acc[t][n][r];
      }
    }
}

// ---- fallback (workspace too small / unexpected shape): exact fp32 ----
__global__ void edge_msg_naive(const float* __restrict__ Vtx, const float* __restrict__ Xe,
                               const float* __restrict__ W, const float* __restrict__ b,
                               float* __restrict__ out, int E) {
  __shared__ float xs[EDG_D];
  __shared__ float vs[VTX_D];
  int e = blockIdx.x;
  int m = threadIdx.x;
  for (int i = m; i < EDG_D; i += 64) xs[i] = Xe[(size_t)e * EDG_D + i];
  for (int i = m; i < VTX_D; i += 64) vs[i] = Vtx[(size_t)e * VTX_D + i];
  __syncthreads();
  float s = 0.f;
  for (int v = 0; v < VTX_D; ++v) {
    const float* wr = W + (size_t)(m * 64 + v) * EDG_D;
    float p = b[m * 64 + v];
    for (int k = 0; k < EDG_D; ++k) p += xs[k] * wr[k];
    s += p * vs[v];
  }
  out[(size_t)e * MSG_D + m] = s;
}

extern "C" void kernel_launch(void* const* d_in, const int* in_sizes, int n_in,
                              void* d_out, int out_size, void* d_ws, size_t ws_size,
                              hipStream_t stream) {
  const float* Vtx = (const float*)d_in[0];   // [E, 64]
  const float* Xe  = (const float*)d_in[1];   // [E, 128]
  const float* W   = (const float*)d_in[2];   // [4096, 128]
  const float* b   = (const float*)d_in[3];   // [4096]
  float* out = (float*)d_out;

  const int E  = in_sizes[0] / VTX_D;
  const int nW = in_sizes[2];                 // 524288
  const int nb = in_sizes[3];                 // 4096

  const size_t needW = (size_t)(524288 + 4096) * sizeof(f16);   // ~1.01 MB

  if (nW != 524288 || nb != 4096 || ws_size < needW) {
    edge_msg_naive<<<E, 64, 0, stream>>>(Vtx, Xe, W, b, out, E);
    return;
  }

  f16* Wh = (f16*)d_ws;
  f16* Bh = Wh + 524288;

  prep_w<<<258, 256, 0, stream>>>(W, b, Wh, Bh);

  int blocks = (E + 255) / 256;
  edge_msg_lds<<<blocks, 256, 0, stream>>>(Vtx, Xe, Wh, Bh, out, E);
}

// Round 3
// 204.001 us; speedup vs baseline: 1.7227x; 1.0099x over previous
//
#include <hip/hip_runtime.h>
#include <stdint.h>

// EdgeMessage: message[e,m] = sum_v (edges[e,:]@W[m*64+v,:] + b[m*64+v]) * vertices[e,v]
// R9: de-phase the W stream (fix L2 hotspot) + setprio around MFMA cluster.
//  - R8 kept all ~500 resident blocks phase-locked on the SAME 16KB Wh step buffer
//    (launch-synced + vmcnt/barrier pacing) -> L2 channel hotspot -> multi-1000-cyc
//    load latency -> step time ~4700 cyc vs ~700 structural.
//  - v-loop is a commutative sum: block b starts at v0 = blockIdx.x & 63 and wraps.
//    Same-XCD blocks (b = xcd mod 8) sit 8 steps apart -> instantaneous per-XCD
//    footprint ~128 KB spread across all L2 channels. Latency back to ~300 cyc,
//    covered by depth-2 prefetch.
//  - T5: s_setprio(1) around af+MFMA cluster (stage/compute role split exists).
//  - Otherwise identical to R8 (4-wave block, 3x16KB LDS ring, counted vmcnt(4),
//    V transposed in LDS, bias as 2 K-steps).

typedef _Float16 f16;
typedef __attribute__((ext_vector_type(2))) _Float16 f16x2;
typedef __attribute__((ext_vector_type(8))) _Float16 f16x8;
typedef __attribute__((ext_vector_type(4))) float f32x4;

#define MSG_D 64
#define VTX_D 64
#define EDG_D 128

__device__ __forceinline__ f16x8 cvt8(float4 a, float4 d) {
  return (f16x8){(f16)a.x, (f16)a.y, (f16)a.z, (f16)a.w,
                 (f16)d.x, (f16)d.y, (f16)d.z, (f16)d.w};
}

// ---- prep: W -> fragment stream; b -> bias frags (layout same as R5/R6) ----
// Wh granule tid = (v*16 + c)*64 + lane (c = s*4+n): f16[8] =
//   W[(n*16+ln)*64 + v][s*32 + q*8 + j], lane = q*16+ln.
__global__ void prep_w(const float* __restrict__ W, const float* __restrict__ b,
                       f16* __restrict__ Wh, f16* __restrict__ Bh) {
  int tid = blockIdx.x * 256 + threadIdx.x;
  if (tid < 65536) {
    int L = tid & 63, n = (tid >> 6) & 3, s = (tid >> 8) & 3, v = tid >> 10;
    int q = L >> 4, ln = L & 15;
    const float* src = W + (size_t)((n * 16 + ln) * 64 + v) * 128 + s * 32 + q * 8;
    float4 a = *(const float4*)src, d = *(const float4*)(src + 4);
    *(f16x8*)(Wh + (size_t)tid * 8) = cvt8(a, d);
  } else if (tid < 66048) {
    int t2 = tid - 65536;
    int L = t2 & 63, n = (t2 >> 6) & 3, s2 = t2 >> 8;
    int q = L >> 4, ln = L & 15;
    const float* src = b + (n * 16 + ln) * 64 + s2 * 32 + q * 8;
    float4 a = *(const float4*)src, d = *(const float4*)(src + 4);
    *(f16x8*)(Bh + (size_t)t2 * 8) = cvt8(a, d);
  }
}

// async global->LDS, 16B per lane, wave-uniform LDS base (+lane*16 implicit)
typedef __attribute__((address_space(1))) const void GV;
typedef __attribute__((address_space(3))) void LV;
__device__ __forceinline__ void gload_lds16(const void* g, void* l) {
  __builtin_amdgcn_global_load_lds((GV*)g, (LV*)l, 16, 0, 0);
}

// ---- main kernel: 256 threads = 4 waves; LDS-shared staggered W stream ----
__global__ __launch_bounds__(256, 2) void edge_msg_lds(
    const float* __restrict__ Vtx, const float* __restrict__ Xe,
    const f16* __restrict__ Wh, const f16* __restrict__ Bh,
    float* __restrict__ out, int E)
{
  __shared__ f16 Wsh[3 * 8192];   // 48 KB: ring of 3 step-buffers (16 KB each)
  __shared__ f16 Vt[64 * 256];    // 32 KB: V transposed f16 [v][local_e]

  const int tid = threadIdx.x;
  const int wid = tid >> 6, lane = tid & 63;
  const int q = lane >> 4, ln = lane & 15;
  const int eblk = blockIdx.x * 256;
  const int eoff = eblk + wid * 64;
  const int v0 = blockIdx.x & 63;   // per-block W-stream phase (sum over v commutes)

  // ---- X fragments f16 (A[m=ln][k=q*8+j] per t,s), rows clamped ----
  int er[4];
  f16x8 xh[4][4];
  #pragma unroll
  for (int t = 0; t < 4; ++t) {
    int e = eoff + 16 * t + ln;
    er[t] = e < E ? e : E - 1;
    const float* xr = Xe + (size_t)er[t] * EDG_D;
    #pragma unroll
    for (int s = 0; s < 4; ++s) {
      float4 a = *(const float4*)(xr + s * 32 + q * 8);
      float4 d = *(const float4*)(xr + s * 32 + q * 8 + 4);
      xh[t][s] = cvt8(a, d);
    }
  }

  // ---- stage V transposed (each thread stages its own local edge row) ----
  {
    int e = eblk + tid;
    int ec = e < E ? e : E - 1;
    const float* vr = Vtx + (size_t)ec * VTX_D;
    #pragma unroll
    for (int k = 0; k < 16; ++k) {
      float4 a = *(const float4*)(vr + k * 4);
      Vt[(k * 4 + 0) * 256 + tid] = (f16)a.x;
      Vt[(k * 4 + 1) * 256 + tid] = (f16)a.y;
      Vt[(k * 4 + 2) * 256 + tid] = (f16)a.z;
      Vt[(k * 4 + 3) * 256 + tid] = (f16)a.w;
    }
  }

  f32x4 acc[4][4];
  #pragma unroll
  for (int t = 0; t < 4; ++t)
    #pragma unroll
    for (int n = 0; n < 4; ++n) acc[t][n] = (f32x4){0.f, 0.f, 0.f, 0.f};

  // V writes visible to all waves before loop
  asm volatile("s_waitcnt lgkmcnt(0)" ::: "memory");
  __builtin_amdgcn_s_barrier();
  asm volatile("" ::: "memory");

  // ---- prefetch logical steps 0,1 (physical v0, v0+1) ----
  // Wh bytes: granule (v,c) at v*16384 + c*1024 + lane*16; wave wid stages c=wid*4..+3
  {
    const size_t wl = (size_t)(wid * 4) * 1024 + (size_t)lane * 16;
    const char* g0 = (const char*)Wh + (size_t)v0 * 16384 + wl;
    const char* g1 = (const char*)Wh + (size_t)((v0 + 1) & 63) * 16384 + wl;
    char* lbase = (char*)&Wsh[0] + (wid * 4) * 1024;
    #pragma unroll
    for (int c = 0; c < 4; ++c) gload_lds16(g0 + c * 1024, lbase + c * 1024);
    #pragma unroll
    for (int c = 0; c < 4; ++c) gload_lds16(g1 + c * 1024, lbase + 2 * 8192 + c * 1024);
  }

  int bo = 0;  // f16 offset of current step buffer in Wsh (0 / 8192 / 16384)

  #pragma unroll 1
  for (int i = 0; i < 64; ++i) {
    const int v = (v0 + i) & 63;   // physical W step this iteration consumes

    // own granules for step i complete (4 newer stay in flight), then block sync
    if (i == 63) asm volatile("s_waitcnt vmcnt(0)" ::: "memory");
    else         asm volatile("s_waitcnt vmcnt(4)" ::: "memory");
    __builtin_amdgcn_s_barrier();
    asm volatile("" ::: "memory");   // no LDS reads / stage issues above this point

    // stage logical step i+2 (physical (v0+i+2)&63) into buf (i+2)%3
    if (i < 62) {
      int so = bo + 2 * 8192;
      if (so >= 3 * 8192) so -= 3 * 8192;
      const char* gbase = (const char*)Wh + (size_t)((v0 + i + 2) & 63) * 16384 +
                          (size_t)(wid * 4) * 1024 + (size_t)lane * 16;
      char* lbase = (char*)&Wsh[so] + (wid * 4) * 1024;
      #pragma unroll
      for (int c = 0; c < 4; ++c) gload_lds16(gbase + c * 1024, lbase + c * 1024);
    }

    // per-edge V broadcast for this v (from transposed LDS, conflict-free)
    f16x2 hv[4];
    #pragma unroll
    for (int t = 0; t < 4; ++t) {
      f16 h = Vt[v * 256 + wid * 64 + 16 * t + ln];
      hv[t] = (f16x2){h, h};
    }

    __builtin_amdgcn_s_setprio(1);
    const f16* wb = &Wsh[bo + lane * 8];
    #pragma unroll
    for (int s = 0; s < 4; ++s) {
      f16x8 bf[4];
      #pragma unroll
      for (int n = 0; n < 4; ++n) bf[n] = *(const f16x8*)(wb + (s * 4 + n) * 512);

      f16x8 af[4];
      #pragma unroll
      for (int t = 0; t < 4; ++t) {
        union { f16x8 v8; f16x2 h2[4]; } x, r;
        x.v8 = xh[t][s];
        r.h2[0] = hv[t] * x.h2[0];
        r.h2[1] = hv[t] * x.h2[1];
        r.h2[2] = hv[t] * x.h2[2];
        r.h2[3] = hv[t] * x.h2[3];
        af[t] = r.v8;
      }
      #pragma unroll
      for (int n = 0; n < 4; ++n)
        #pragma unroll
        for (int t = 0; t < 4; ++t)
          acc[t][n] = __builtin_amdgcn_mfma_f32_16x16x32_f16(af[t], bf[n], acc[t][n], 0, 0, 0);
    }
    __builtin_amdgcn_s_setprio(0);

    bo += 8192;
    if (bo >= 3 * 8192) bo -= 3 * 8192;
  }

  // ---- bias: 2 K-steps, A = V-frags (original layout), B = Bh frags ----
  #pragma unroll
  for (int s2 = 0; s2 < 2; ++s2) {
    f16x8 av[4];
    #pragma unroll
    for (int t = 0; t < 4; ++t) {
      const float* vr2 = Vtx + (size_t)er[t] * VTX_D + s2 * 32 + q * 8;
      float4 a = *(const float4*)vr2, d = *(const float4*)(vr2 + 4);
      av[t] = cvt8(a, d);
    }
    #pragma unroll
    for (int n = 0; n < 4; ++n) {
      f16x8 bfb = *(const f16x8*)(Bh + (size_t)((s2 * 4 + n) * 64 + lane) * 8);
      #pragma unroll
      for (int t = 0; t < 4; ++t)
        acc[t][n] = __builtin_amdgcn_mfma_f32_16x16x32_f16(av[t], bfb, acc[t][n], 0, 0, 0);
    }
  }

  // ---- store: C layout col=lane&15 (m), row=q*4+r (edge) [m89-verified] ----
  #pragma unroll
  for (int t = 0; t < 4; ++t)
    #pragma unroll
    for (int r = 0; r < 4; ++r) {
      int e = eoff + 16 * t + 4 * q + r;
      if (e < E) {
        float* orow = out + (size_t)e * MSG_D;
        #pragma unroll
        for (int n = 0; n < 4; ++n) orow[n * 16 + ln] = acc[t][n][r];
      }
    }
}

// ---- fallback (workspace too small / unexpected shape): exact fp32 ----
__global__ void edge_msg_naive(const float* __restrict__ Vtx, const float* __restrict__ Xe,
                               const float* __restrict__ W, const float* __restrict__ b,
                               float* __restrict__ out, int E) {
  __shared__ float xs[EDG_D];
  __shared__ float vs[VTX_D];
  int e = blockIdx.x;
  int m = threadIdx.x;
  for (int i = m; i < EDG_D; i += 64) xs[i] = Xe[(size_t)e * EDG_D + i];
  for (int i = m; i < VTX_D; i += 64) vs[i] = Vtx[(size_t)e * VTX_D + i];
  __syncthreads();
  float s = 0.f;
  for (int v = 0; v < VTX_D; ++v) {
    const float* wr = W + (size_t)(m * 64 + v) * EDG_D;
    float p = b[m * 64 + v];
    for (int k = 0; k < EDG_D; ++k) p += xs[k] * wr[k];
    s += p * vs[v];
  }
  out[(size_t)e * MSG_D + m] = s;
}

extern "C" void kernel_launch(void* const* d_in, const int* in_sizes, int n_in,
                              void* d_out, int out_size, void* d_ws, size_t ws_size,
                              hipStream_t stream) {
  const float* Vtx = (const float*)d_in[0];   // [E, 64]
  const float* Xe  = (const float*)d_in[1];   // [E, 128]
  const float* W   = (const float*)d_in[2];   // [4096, 128]
  const float* b   = (const float*)d_in[3];   // [4096]
  float* out = (float*)d_out;

  const int E  = in_sizes[0] / VTX_D;
  const int nW = in_sizes[2];                 // 524288
  const int nb = in_sizes[3];                 // 4096

  const size_t needW = (size_t)(524288 + 4096) * sizeof(f16);   // ~1.01 MB

  if (nW != 524288 || nb != 4096 || ws_size < needW) {
    edge_msg_naive<<<E, 64, 0, stream>>>(Vtx, Xe, W, b, out, E);
    return;
  }

  f16* Wh = (f16*)d_ws;
  f16* Bh = Wh + 524288;

  prep_w<<<258, 256, 0, stream>>>(W, b, Wh, Bh);

  int blocks = (E + 255) / 256;
  edge_msg_lds<<<blocks, 256, 0, stream>>>(Vtx, Xe, Wh, Bh, out, E);
}